// Round 11
// baseline (277.553 us; speedup 1.0000x reference)
//
#include <hip/hip_runtime.h>
#include <cstdint>
#include <cstddef>

typedef unsigned short u16;
typedef __attribute__((ext_vector_type(8))) short bf16x8;   // 8 bf16 in 4 VGPRs
typedef __attribute__((ext_vector_type(8))) unsigned short u16x8;
typedef __attribute__((ext_vector_type(4))) float f32x4;

static constexpr int Bc = 2, Sc = 2048, Ec = 1024, Hc = 16, Dc = 64;

__device__ __forceinline__ float bf2f(u16 v) {
    unsigned u = ((unsigned)v) << 16;
    float f; __builtin_memcpy(&f, &u, 4); return f;
}
__device__ __forceinline__ u16 f2bf(float f) {  // round-nearest-even
    unsigned u; __builtin_memcpy(&u, &f, 4);
    u += 0x7fffu + ((u >> 16) & 1u);
    return (u16)(u >> 16);
}
__device__ __forceinline__ bf16x8 as_bf(u16x8 v) { return __builtin_bit_cast(bf16x8, v); }

// ---------------------------------------------------------------- cast x -> bf16
__global__ void cast_f32_bf16(const float* __restrict__ in, u16* __restrict__ out, int n) {
    int i = (blockIdx.x * blockDim.x + threadIdx.x) * 4;
    if (i < n) {
        float4 v = *reinterpret_cast<const float4*>(in + i);
        ushort4 o;
        o.x = f2bf(v.x); o.y = f2bf(v.y); o.z = f2bf(v.z); o.w = f2bf(v.w);
        *reinterpret_cast<ushort4*>(out + i) = o;
    }
}

// ------------------------------------------- transpose [R][C] f32 -> [C][R] bf16
__global__ void transpose_cast(const float* __restrict__ in, u16* __restrict__ out,
                               int R, int C) {
    __shared__ float tile[32][33];
    int tx = threadIdx.x, ty = threadIdx.y;
    int c0 = blockIdx.x * 32, r0 = blockIdx.y * 32;
    tile[ty][tx] = in[(size_t)(r0 + ty) * C + c0 + tx];
    __syncthreads();
    out[(size_t)(c0 + ty) * R + r0 + tx] = f2bf(tile[tx][ty]);
}

// ------------------------------------------------------------------ bf16 GEMM
// C[M][N] = A[M][K] * Bt[N][K]^T.  128x128 tile, BK=32, 4 waves, 16x16x32 MFMA.
// m97 structure: global_load_lds width-16 staging into linear (unpadded) LDS.
template <int OUT_BF16>
__global__ __launch_bounds__(256) void gemm_bt(const u16* __restrict__ A,
                                               const u16* __restrict__ Bt,
                                               void* __restrict__ Cout,
                                               int M, int N, int K) {
    constexpr int BK = 32;
    __shared__ u16 As[128][BK];
    __shared__ u16 Bs[128][BK];
    const int m0 = blockIdx.x * 128, n0 = blockIdx.y * 128;
    const int t = threadIdx.x;
    const int lane = t & 63, w = t >> 6;
    const int wr = w >> 1, wc = w & 1;
    const int l15 = lane & 15, lhi = lane >> 4;
    const int lrow = lane >> 2, lcol = (lane & 3) * 8;   // 4 lanes per 32-u16 row

    f32x4 acc[4][4] = {};

    for (int k0 = 0; k0 < K; k0 += BK) {
#pragma unroll
        for (int i = 0; i < 2; i++) {
            const u16* ap = A + (size_t)(m0 + w * 32 + i * 16 + lrow) * K + k0 + lcol;
            __builtin_amdgcn_global_load_lds(
                (const __attribute__((address_space(1))) unsigned int*)ap,
                (__attribute__((address_space(3))) unsigned int*)&As[w * 32 + i * 16][0],
                16, 0, 0);
            const u16* bp = Bt + (size_t)(n0 + w * 32 + i * 16 + lrow) * K + k0 + lcol;
            __builtin_amdgcn_global_load_lds(
                (const __attribute__((address_space(1))) unsigned int*)bp,
                (__attribute__((address_space(3))) unsigned int*)&Bs[w * 32 + i * 16][0],
                16, 0, 0);
        }
        __syncthreads();

        bf16x8 af[4], bfv[4];
#pragma unroll
        for (int i = 0; i < 4; i++)
            af[i] = as_bf(*reinterpret_cast<const u16x8*>(&As[wr * 64 + i * 16 + l15][lhi * 8]));
#pragma unroll
        for (int j = 0; j < 4; j++)
            bfv[j] = as_bf(*reinterpret_cast<const u16x8*>(&Bs[wc * 64 + j * 16 + l15][lhi * 8]));
#pragma unroll
        for (int i = 0; i < 4; i++)
#pragma unroll
            for (int j = 0; j < 4; j++)
                acc[i][j] = __builtin_amdgcn_mfma_f32_16x16x32_bf16(af[i], bfv[j], acc[i][j], 0, 0, 0);
        __syncthreads();
    }

#pragma unroll
    for (int i = 0; i < 4; i++)
#pragma unroll
        for (int j = 0; j < 4; j++)
#pragma unroll
            for (int r = 0; r < 4; r++) {
                int row = m0 + wr * 64 + i * 16 + lhi * 4 + r;
                int col = n0 + wc * 64 + j * 16 + l15;
                float v = acc[i][j][r];
                if (OUT_BF16)
                    ((u16*)Cout)[(size_t)row * N + col] = f2bf(v);
                else
                    ((float*)Cout)[(size_t)row * N + col] = v;
            }
}

// -------------------------------------------- RoPE + head pack  qkv -> Q,K
// Q gets *0.125*log2(e) so attention can use exp2 with a fixed base.
__global__ void rope_pack(const u16* __restrict__ qkv,
                          const float* __restrict__ fcos, const float* __restrict__ fsin,
                          u16* __restrict__ Qb, u16* __restrict__ Kb) {
    int g = blockIdx.x * blockDim.x + threadIdx.x;
    int dg = g & 3;
    int h = (g >> 2) & 15;
    int row = g >> 6;
    int b = row >> 11, s = row & 2047;
    const float QS = 0.18033688011f;   // 0.125 * log2(e)

    const u16* qp = qkv + (size_t)row * 3072 + h * 64 + dg * 16;
    u16x8 q0 = *reinterpret_cast<const u16x8*>(qp);
    u16x8 q1 = *reinterpret_cast<const u16x8*>(qp + 8);
    u16x8 k0 = *reinterpret_cast<const u16x8*>(qp + 1024);
    u16x8 k1 = *reinterpret_cast<const u16x8*>(qp + 1032);

    const float* cp = fcos + (size_t)s * 32 + dg * 8;
    const float* sp = fsin + (size_t)s * 32 + dg * 8;
    float cs[8], sn[8];
#pragma unroll
    for (int p = 0; p < 8; p++) { cs[p] = cp[p]; sn[p] = sp[p]; }

    u16 qi[16], ki[16], qo[16], ko[16];
#pragma unroll
    for (int j = 0; j < 8; j++) { qi[j] = q0[j]; qi[j + 8] = q1[j]; ki[j] = k0[j]; ki[j + 8] = k1[j]; }
#pragma unroll
    for (int p = 0; p < 8; p++) {
        float x0 = bf2f(qi[2 * p]), x1 = bf2f(qi[2 * p + 1]);
        qo[2 * p]     = f2bf((x0 * cs[p] - x1 * sn[p]) * QS);
        qo[2 * p + 1] = f2bf((x0 * sn[p] + x1 * cs[p]) * QS);
        float y0 = bf2f(ki[2 * p]), y1 = bf2f(ki[2 * p + 1]);
        ko[2 * p]     = f2bf(y0 * cs[p] - y1 * sn[p]);
        ko[2 * p + 1] = f2bf(y0 * sn[p] + y1 * cs[p]);
    }

    size_t dst = ((size_t)(b * 16 + h) * 2048 + s) * 64 + dg * 16;
    u16x8 qa, qb2, ka, kb2;
#pragma unroll
    for (int j = 0; j < 8; j++) { qa[j] = qo[j]; qb2[j] = qo[j + 8]; ka[j] = ko[j]; kb2[j] = ko[j + 8]; }
    *reinterpret_cast<u16x8*>(Qb + dst) = qa;
    *reinterpret_cast<u16x8*>(Qb + dst + 8) = qb2;
    *reinterpret_cast<u16x8*>(Kb + dst) = ka;
    *reinterpret_cast<u16x8*>(Kb + dst + 8) = kb2;
}

// ---------------------------------------------- V transpose: qkvb -> VT [BH][D][S]
__global__ __launch_bounds__(256) void vtrans(const u16* __restrict__ qkv,
                                              u16* __restrict__ VT) {
    __shared__ u16 tile[64][70];
    const int bh = blockIdx.y, b = bh >> 4, h = bh & 15;
    const int s0 = blockIdx.x * 64;
    const int t = threadIdx.x;
    const int si = t >> 2, dc = (t & 3) * 16;
    const u16* src = qkv + (size_t)(b * 2048 + s0 + si) * 3072 + 2048 + h * 64 + dc;
    *reinterpret_cast<u16x8*>(&tile[si][dc])     = *reinterpret_cast<const u16x8*>(src);
    *reinterpret_cast<u16x8*>(&tile[si][dc + 8]) = *reinterpret_cast<const u16x8*>(src + 8);
    __syncthreads();
    const int d = t >> 2, sc = (t & 3) * 16;
    u16x8 v0, v1;
#pragma unroll
    for (int j = 0; j < 8; j++) { v0[j] = tile[sc + j][d]; v1[j] = tile[sc + 8 + j][d]; }
    size_t dst = ((size_t)bh * 64 + d) * 2048 + s0 + sc;
    *reinterpret_cast<u16x8*>(VT + dst)     = v0;
    *reinterpret_cast<u16x8*>(VT + dst + 8) = v1;
}

// ------------------------------------------------------- flash attention (causal)
// attn_fwd7 = fwd6 skeleton + fwd3 tile body.
// Skeleton (measured r10): block owns complementary chunk pair (63-p, p), 33 KV
// tiles total split 9/8/8/8 across 4 waves (<=2 segments/wave); LDS atomicAdd
// merge of partial (o,l); fixed-base softmax exp2(s-14); ones-MFMA row-sum.
// Body (measured r3, 4.9 kcyc/tile serial): register double-buffered K prefetch
// (next tile's K loads issue before current tile's QK MFMAs), V loads hoisted
// after QK so L2 latency hides under mask/exp/P-store.
__device__ __forceinline__ void load_ktile7(const u16* __restrict__ Kp, int t0,
                                            int l15, int lhi, bf16x8 (&kd)[8]) {
#pragma unroll
    for (int cb = 0; cb < 4; cb++) {
        const u16* kp = Kp + (size_t)(t0 + cb * 16 + l15) * 64 + lhi * 8;
        kd[cb * 2 + 0] = as_bf(*reinterpret_cast<const u16x8*>(kp));
        kd[cb * 2 + 1] = as_bf(*reinterpret_cast<const u16x8*>(kp + 32));
    }
}

__device__ __forceinline__ void attn_tile7(int t0, int nt0, bool diag, int q0,
                                           const u16* __restrict__ Kp,
                                           const u16* __restrict__ Vp,
                                           int l15, int lhi,
                                           const bf16x8 (&kc_)[8], bf16x8 (&kn_)[8],
                                           const bf16x8 (&qf)[2][2], bf16x8 onesf,
                                           f32x4 (&o)[2][4], f32x4 (&os)[2],
                                           u16* __restrict__ PsW) {
    // prefetch next K tile (registers)
    load_ktile7(Kp, nt0, l15, lhi, kn_);

    // QK^T; C-init = -14 folds the fixed softmax base
    f32x4 s[2][4];
#pragma unroll
    for (int qa = 0; qa < 2; qa++)
#pragma unroll
        for (int cb = 0; cb < 4; cb++) {
            f32x4 v = {-14.0f, -14.0f, -14.0f, -14.0f};
            v = __builtin_amdgcn_mfma_f32_16x16x32_bf16(qf[qa][0], kc_[cb * 2 + 0], v, 0, 0, 0);
            v = __builtin_amdgcn_mfma_f32_16x16x32_bf16(qf[qa][1], kc_[cb * 2 + 1], v, 0, 0, 0);
            s[qa][cb] = v;
        }

    // V^T fragments for THIS tile (latency hides under mask/exp/store phase)
    bf16x8 vf[8];
#pragma unroll
    for (int db = 0; db < 4; db++)
#pragma unroll
        for (int kc2 = 0; kc2 < 2; kc2++)
            vf[db * 2 + kc2] = as_bf(*reinterpret_cast<const u16x8*>(
                Vp + (size_t)(db * 16 + l15) * 2048 + t0 + kc2 * 32 + lhi * 8));

    if (diag) {
#pragma unroll
        for (int qa = 0; qa < 2; qa++)
#pragma unroll
            for (int cb = 0; cb < 4; cb++) {
                const int tg = t0 + cb * 16 + l15;
#pragma unroll
                for (int r = 0; r < 4; r++) {
                    const int qg = q0 + qa * 16 + lhi * 4 + r;
                    if (tg > qg) s[qa][cb][r] = -1e30f;
                }
            }
    }

    // P = exp2(s), store truncated bf16 to wave-private LDS
#pragma unroll
    for (int qa = 0; qa < 2; qa++)
#pragma unroll
        for (int cb = 0; cb < 4; cb++)
#pragma unroll
            for (int r = 0; r < 4; r++) {
                float p = __builtin_amdgcn_exp2f(s[qa][cb][r]);
                unsigned pb; __builtin_memcpy(&pb, &p, 4);
                PsW[(qa * 16 + lhi * 4 + r) * 70 + cb * 16 + l15] = (u16)(pb >> 16);
            }
    asm volatile("s_waitcnt lgkmcnt(0)" ::: "memory");
    __builtin_amdgcn_sched_barrier(0);   // rule #18: keep MFMA below the waitcnt

    // PV + row-sum via ones fragment
#pragma unroll
    for (int qa = 0; qa < 2; qa++) {
        bf16x8 pf0 = as_bf(*reinterpret_cast<const u16x8*>(&PsW[(qa * 16 + l15) * 70 + lhi * 8]));
        bf16x8 pf1 = as_bf(*reinterpret_cast<const u16x8*>(&PsW[(qa * 16 + l15) * 70 + 32 + lhi * 8]));
        os[qa] = __builtin_amdgcn_mfma_f32_16x16x32_bf16(pf0, onesf, os[qa], 0, 0, 0);
        os[qa] = __builtin_amdgcn_mfma_f32_16x16x32_bf16(pf1, onesf, os[qa], 0, 0, 0);
#pragma unroll
        for (int db = 0; db < 4; db++) {
            o[qa][db] = __builtin_amdgcn_mfma_f32_16x16x32_bf16(pf0, vf[db * 2 + 0], o[qa][db], 0, 0, 0);
            o[qa][db] = __builtin_amdgcn_mfma_f32_16x16x32_bf16(pf1, vf[db * 2 + 1], o[qa][db], 0, 0, 0);
        }
    }
}

__global__ __launch_bounds__(256) void attn_fwd7(const u16* __restrict__ Qb,
                                                 const u16* __restrict__ Kb,
                                                 const u16* __restrict__ VTb,
                                                 u16* __restrict__ attn_out) {
    __shared__ u16 Ps[4][32 * 70];      // per-wave P tile (stride 70: 0 conflicts)
    __shared__ float Om[2][32][64];     // per-chunk partial O accumulator
    __shared__ float Ol[2][32];         // per-chunk partial l accumulator

    const int t = threadIdx.x, lane = t & 63, w = t >> 6;
    const int l15 = lane & 15, lhi = lane >> 4;

    const int id = blockIdx.x;
    const int bh = (id & 7) + 8 * ((id >> 3) & 3);   // 4 heads per XCD
    const int p = id >> 5;                           // pair index 0..31
    const int b = bh >> 4, h = bh & 15;
    const u16* Qp = Qb + (size_t)bh * (Sc * Dc);
    const u16* Kp = Kb + (size_t)bh * (Sc * Dc);
    const u16* Vp = VTb + (size_t)bh * (Sc * Dc);
    u16* PsW = &Ps[w][0];

    // zero the merge accumulators
    for (int i = t; i < 2 * 32 * 64; i += 256) ((float*)Om)[i] = 0.f;
    if (t < 64) ((float*)Ol)[t] = 0.f;
    __syncthreads();

    u16x8 onesu;
#pragma unroll
    for (int j = 0; j < 8; j++) onesu[j] = 0x3F80;
    const bf16x8 onesf = as_bf(onesu);

    const int nh = ((63 - p) >> 1) + 1;   // tiles in hi chunk (17..32); lo = 33-nh
    const int g0 = w ? 9 + (w - 1) * 8 : 0;
    const int g1 = w ? g0 + 8 : 9;

    for (int seg = 0; seg < 2; seg++) {
        const int a0 = seg ? (g0 > nh ? g0 : nh) : g0;
        const int a1 = seg ? g1 : (g1 < nh ? g1 : nh);
        if (a0 >= a1) continue;
        const int qc = seg ? p : 63 - p;
        const int q0 = qc * 32;
        const int ktoff = seg ? nh : 0;
        const int ntl = seg ? 33 - nh : nh;

        // Q fragments for this chunk
        bf16x8 qf[2][2];
#pragma unroll
        for (int qa = 0; qa < 2; qa++)
#pragma unroll
            for (int kc = 0; kc < 2; kc++)
                qf[qa][kc] = as_bf(*reinterpret_cast<const u16x8*>(
                    Qp + (size_t)(q0 + qa * 16 + l15) * 64 + kc * 32 + lhi * 8));

        f32x4 o[2][4] = {};
        f32x4 os[2] = {};

        // K double-buffer: 2-step unrolled swap loop (static frag indexing, rule #20)
        bf16x8 ka[8], kb2[8];
        const int lastkt = ntl - 1;
        load_ktile7(Kp, (a0 - ktoff) * 64, l15, lhi, ka);

        int g = a0;
        while (true) {
            int kt = g - ktoff;
            int t0 = kt * 64;
            int nt0 = (kt < lastkt && g + 1 < a1) ? t0 + 64 : t0;
            attn_tile7(t0, nt0, kt == lastkt, q0, Kp, Vp, l15, lhi, ka, kb2, qf, onesf, o, os, PsW);
            if (++g >= a1) break;
            kt = g - ktoff;
            t0 = kt * 64;
            nt0 = (kt < lastkt && g + 1 < a1) ? t0 + 64 : t0;
            attn_tile7(t0, nt0, kt == lastkt, q0, Kp, Vp, l15, lhi, kb2, ka, qf, onesf, o, os, PsW);
            if (++g >= a1) break;
        }

        // ---- dump this segment's partials (ds_add_f32; order-independent sums)
        const int ci = seg;
#pragma unroll
        for (int qa = 0; qa < 2; qa++)
#pragma unroll
            for (int r = 0; r < 4; r++) {
                const int row = qa * 16 + lhi * 4 + r;
                if (l15 == 0) atomicAdd(&Ol[ci][row], os[qa][r]);
#pragma unroll
                for (int db = 0; db < 4; db++)
                    atomicAdd(&Om[ci][row][db * 16 + l15], o[qa][db][r]);
            }
    }

    __syncthreads();   // all partials merged

    // ---- epilogue: wave pair per chunk; normalize, write [B*S][E] bf16
    {
        const int c = w >> 1, sub = w & 1;
        const int row = sub * 16 + (lane >> 2);
        const int colq = (lane & 3) * 16;
        const int qg = (c ? p : 63 - p) * 32 + row;
        const float inv = 1.0f / Ol[c][row];
        f32x4 v0 = *reinterpret_cast<const f32x4*>(&Om[c][row][colq]);
        f32x4 v1 = *reinterpret_cast<const f32x4*>(&Om[c][row][colq + 4]);
        f32x4 v2 = *reinterpret_cast<const f32x4*>(&Om[c][row][colq + 8]);
        f32x4 v3 = *reinterpret_cast<const f32x4*>(&Om[c][row][colq + 12]);
        u16x8 o0, o1;
#pragma unroll
        for (int j = 0; j < 4; j++) {
            o0[j]     = f2bf(v0[j] * inv);
            o0[j + 4] = f2bf(v1[j] * inv);
            o1[j]     = f2bf(v2[j] * inv);
            o1[j + 4] = f2bf(v3[j] * inv);
        }
        const size_t obase = ((size_t)(b * 2048 + qg)) * 1024 + h * 64 + colq;
        *reinterpret_cast<u16x8*>(attn_out + obase)     = o0;
        *reinterpret_cast<u16x8*>(attn_out + obase + 8) = o1;
    }
}

// ---------------------------------------------------------------------- launch
extern "C" void kernel_launch(void* const* d_in, const int* in_sizes, int n_in,
                              void* d_out, int out_size, void* d_ws, size_t ws_size,
                              hipStream_t stream) {
    const float* x     = (const float*)d_in[0];
    const float* w_qkv = (const float*)d_in[1];
    const float* w_out = (const float*)d_in[2];
    const float* fcos  = (const float*)d_in[3];
    const float* fsin  = (const float*)d_in[4];
    float* out = (float*)d_out;

    char* ws = (char*)d_ws;
    u16* xb    = (u16*)(ws);                       //  8,388,608 B
    u16* wqkvT = (u16*)(ws + 8388608);             //  6,291,456 B
    u16* woutT = (u16*)(ws + 14680064);            //  2,097,152 B
    u16* qkvb  = (u16*)(ws + 16777216);            // 25,165,824 B
    u16* Qb    = (u16*)(ws + 41943040);            //  8,388,608 B
    u16* Kb    = (u16*)(ws + 50331648);            //  8,388,608 B
    u16* VTb   = (u16*)(ws + 58720256);            //  8,388,608 B  (V transposed)
    u16* attnb = (u16*)(ws + 67108864);            //  8,388,608 B

    cast_f32_bf16<<<4096, 256, 0, stream>>>(x, xb, Bc * Sc * Ec);
    transpose_cast<<<dim3(96, 32), dim3(32, 32), 0, stream>>>(w_qkv, wqkvT, 1024, 3072);
    transpose_cast<<<dim3(32, 32), dim3(32, 32), 0, stream>>>(w_out, woutT, 1024, 1024);
    gemm_bt<1><<<dim3(32, 24), 256, 0, stream>>>(xb, wqkvT, qkvb, 4096, 3072, 1024);
    rope_pack<<<1024, 256, 0, stream>>>(qkvb, fcos, fsin, Qb, Kb);
    vtrans<<<dim3(32, 32), 256, 0, stream>>>(qkvb, VTb);
    attn_fwd7<<<1024, 256, 0, stream>>>(Qb, Kb, VTb, attnb);
    gemm_bt<0><<<dim3(32, 8), 256, 0, stream>>>(attnb, woutT, out, 4096, 1024, 1024);
}

// Round 12
// 219.335 us; speedup vs baseline: 1.2654x; 1.2654x over previous
//
#include <hip/hip_runtime.h>
#include <cstdint>
#include <cstddef>

typedef unsigned short u16;
typedef __attribute__((ext_vector_type(8))) short bf16x8;   // 8 bf16 in 4 VGPRs
typedef __attribute__((ext_vector_type(8))) unsigned short u16x8;
typedef __attribute__((ext_vector_type(4))) float f32x4;

static constexpr int Bc = 2, Sc = 2048, Ec = 1024, Hc = 16, Dc = 64;

__device__ __forceinline__ float bf2f(u16 v) {
    unsigned u = ((unsigned)v) << 16;
    float f; __builtin_memcpy(&f, &u, 4); return f;
}
__device__ __forceinline__ u16 f2bf(float f) {  // round-nearest-even
    unsigned u; __builtin_memcpy(&u, &f, 4);
    u += 0x7fffu + ((u >> 16) & 1u);
    return (u16)(u >> 16);
}
__device__ __forceinline__ bf16x8 as_bf(u16x8 v) { return __builtin_bit_cast(bf16x8, v); }

// ---------------------------------------------------------------- cast x -> bf16
__global__ void cast_f32_bf16(const float* __restrict__ in, u16* __restrict__ out, int n) {
    int i = (blockIdx.x * blockDim.x + threadIdx.x) * 4;
    if (i < n) {
        float4 v = *reinterpret_cast<const float4*>(in + i);
        ushort4 o;
        o.x = f2bf(v.x); o.y = f2bf(v.y); o.z = f2bf(v.z); o.w = f2bf(v.w);
        *reinterpret_cast<ushort4*>(out + i) = o;
    }
}

// ------------------------------------------- transpose [R][C] f32 -> [C][R] bf16
__global__ void transpose_cast(const float* __restrict__ in, u16* __restrict__ out,
                               int R, int C) {
    __shared__ float tile[32][33];
    int tx = threadIdx.x, ty = threadIdx.y;
    int c0 = blockIdx.x * 32, r0 = blockIdx.y * 32;
    tile[ty][tx] = in[(size_t)(r0 + ty) * C + c0 + tx];
    __syncthreads();
    out[(size_t)(c0 + ty) * R + r0 + tx] = f2bf(tile[tx][ty]);
}

// ------------------------------------------------------------------ bf16 GEMM
// C[M][N] = A[M][K] * Bt[N][K]^T.  128x128 tile, BK=64, 4 waves, 16x16x32 MFMA.
// m97 structure (global_load_lds width-16, linear LDS dest) + BK=64 (16 K-iters,
// half the barrier drains) + both-sides XOR chunk swizzle (rule #21): the global
// SOURCE 16B-chunk index is swizzled c ^= (row&7) while the LDS dest stays
// linear; the ds_read side applies the same XOR -> 8-way bank spread (2-way =
// free) instead of the 16-way conflict a linear [128][64] layout would have.
template <int OUT_BF16>
__global__ __launch_bounds__(256) void gemm_bt(const u16* __restrict__ A,
                                               const u16* __restrict__ Bt,
                                               void* __restrict__ Cout,
                                               int M, int N, int K) {
    constexpr int BK = 64;
    __shared__ u16 As[128][BK];   // 16 KB
    __shared__ u16 Bs[128][BK];   // 16 KB
    const int m0 = blockIdx.x * 128, n0 = blockIdx.y * 128;
    const int t = threadIdx.x;
    const int lane = t & 63, w = t >> 6;
    const int wr = w >> 1, wc = w & 1;
    const int l15 = lane & 15, lhi = lane >> 4;
    // staging: 8 lanes per 64-u16 row (128 B), 8 rows per global_load_lds
    const int srow = lane >> 3;                      // 0..7
    const int schunk = (lane & 7) ^ (lane >> 3);     // swizzled source chunk (XOR bijection per row)

    f32x4 acc[4][4] = {};

    for (int k0 = 0; k0 < K; k0 += BK) {
#pragma unroll
        for (int i = 0; i < 4; i++) {
            // rows w*32+i*8 .. +8 ; LDS dest linear (lane*16B), source chunk swizzled
            const u16* ap = A + (size_t)(m0 + w * 32 + i * 8 + srow) * K + k0 + schunk * 8;
            __builtin_amdgcn_global_load_lds(
                (const __attribute__((address_space(1))) unsigned int*)ap,
                (__attribute__((address_space(3))) unsigned int*)&As[w * 32 + i * 8][0],
                16, 0, 0);
            const u16* bp = Bt + (size_t)(n0 + w * 32 + i * 8 + srow) * K + k0 + schunk * 8;
            __builtin_amdgcn_global_load_lds(
                (const __attribute__((address_space(1))) unsigned int*)bp,
                (__attribute__((address_space(3))) unsigned int*)&Bs[w * 32 + i * 8][0],
                16, 0, 0);
        }
        __syncthreads();

#pragma unroll
        for (int kk = 0; kk < 2; kk++) {
            bf16x8 af[4], bfv[4];
#pragma unroll
            for (int i = 0; i < 4; i++) {
                const int row = wr * 64 + i * 16 + l15;
                const int ch = (kk * 4 + lhi) ^ (row & 7);   // read-side swizzle
                af[i] = as_bf(*reinterpret_cast<const u16x8*>(&As[row][ch * 8]));
            }
#pragma unroll
            for (int j = 0; j < 4; j++) {
                const int row = wc * 64 + j * 16 + l15;
                const int ch = (kk * 4 + lhi) ^ (row & 7);
                bfv[j] = as_bf(*reinterpret_cast<const u16x8*>(&Bs[row][ch * 8]));
            }
#pragma unroll
            for (int i = 0; i < 4; i++)
#pragma unroll
                for (int j = 0; j < 4; j++)
                    acc[i][j] = __builtin_amdgcn_mfma_f32_16x16x32_bf16(af[i], bfv[j], acc[i][j], 0, 0, 0);
        }
        __syncthreads();
    }

#pragma unroll
    for (int i = 0; i < 4; i++)
#pragma unroll
        for (int j = 0; j < 4; j++)
#pragma unroll
            for (int r = 0; r < 4; r++) {
                int row = m0 + wr * 64 + i * 16 + lhi * 4 + r;
                int col = n0 + wc * 64 + j * 16 + l15;
                float v = acc[i][j][r];
                if (OUT_BF16)
                    ((u16*)Cout)[(size_t)row * N + col] = f2bf(v);
                else
                    ((float*)Cout)[(size_t)row * N + col] = v;
            }
}

// -------------------------------------------- RoPE + head pack  qkv -> Q,K
// Q gets *0.125*log2(e) so attention can use exp2 with a fixed base.
__global__ void rope_pack(const u16* __restrict__ qkv,
                          const float* __restrict__ fcos, const float* __restrict__ fsin,
                          u16* __restrict__ Qb, u16* __restrict__ Kb) {
    int g = blockIdx.x * blockDim.x + threadIdx.x;
    int dg = g & 3;
    int h = (g >> 2) & 15;
    int row = g >> 6;
    int b = row >> 11, s = row & 2047;
    const float QS = 0.18033688011f;   // 0.125 * log2(e)

    const u16* qp = qkv + (size_t)row * 3072 + h * 64 + dg * 16;
    u16x8 q0 = *reinterpret_cast<const u16x8*>(qp);
    u16x8 q1 = *reinterpret_cast<const u16x8*>(qp + 8);
    u16x8 k0 = *reinterpret_cast<const u16x8*>(qp + 1024);
    u16x8 k1 = *reinterpret_cast<const u16x8*>(qp + 1032);

    const float* cp = fcos + (size_t)s * 32 + dg * 8;
    const float* sp = fsin + (size_t)s * 32 + dg * 8;
    float cs[8], sn[8];
#pragma unroll
    for (int p = 0; p < 8; p++) { cs[p] = cp[p]; sn[p] = sp[p]; }

    u16 qi[16], ki[16], qo[16], ko[16];
#pragma unroll
    for (int j = 0; j < 8; j++) { qi[j] = q0[j]; qi[j + 8] = q1[j]; ki[j] = k0[j]; ki[j + 8] = k1[j]; }
#pragma unroll
    for (int p = 0; p < 8; p++) {
        float x0 = bf2f(qi[2 * p]), x1 = bf2f(qi[2 * p + 1]);
        qo[2 * p]     = f2bf((x0 * cs[p] - x1 * sn[p]) * QS);
        qo[2 * p + 1] = f2bf((x0 * sn[p] + x1 * cs[p]) * QS);
        float y0 = bf2f(ki[2 * p]), y1 = bf2f(ki[2 * p + 1]);
        ko[2 * p]     = f2bf(y0 * cs[p] - y1 * sn[p]);
        ko[2 * p + 1] = f2bf(y0 * sn[p] + y1 * cs[p]);
    }

    size_t dst = ((size_t)(b * 16 + h) * 2048 + s) * 64 + dg * 16;
    u16x8 qa, qb2, ka, kb2;
#pragma unroll
    for (int j = 0; j < 8; j++) { qa[j] = qo[j]; qb2[j] = qo[j + 8]; ka[j] = ko[j]; kb2[j] = ko[j + 8]; }
    *reinterpret_cast<u16x8*>(Qb + dst) = qa;
    *reinterpret_cast<u16x8*>(Qb + dst + 8) = qb2;
    *reinterpret_cast<u16x8*>(Kb + dst) = ka;
    *reinterpret_cast<u16x8*>(Kb + dst + 8) = kb2;
}

// ---------------------------------------------- V transpose: qkvb -> VT [BH][D][S]
__global__ __launch_bounds__(256) void vtrans(const u16* __restrict__ qkv,
                                              u16* __restrict__ VT) {
    __shared__ u16 tile[64][70];
    const int bh = blockIdx.y, b = bh >> 4, h = bh & 15;
    const int s0 = blockIdx.x * 64;
    const int t = threadIdx.x;
    const int si = t >> 2, dc = (t & 3) * 16;
    const u16* src = qkv + (size_t)(b * 2048 + s0 + si) * 3072 + 2048 + h * 64 + dc;
    *reinterpret_cast<u16x8*>(&tile[si][dc])     = *reinterpret_cast<const u16x8*>(src);
    *reinterpret_cast<u16x8*>(&tile[si][dc + 8]) = *reinterpret_cast<const u16x8*>(src + 8);
    __syncthreads();
    const int d = t >> 2, sc = (t & 3) * 16;
    u16x8 v0, v1;
#pragma unroll
    for (int j = 0; j < 8; j++) { v0[j] = tile[sc + j][d]; v1[j] = tile[sc + 8 + j][d]; }
    size_t dst = ((size_t)bh * 64 + d) * 2048 + s0 + sc;
    *reinterpret_cast<u16x8*>(VT + dst)     = v0;
    *reinterpret_cast<u16x8*>(VT + dst + 8) = v1;
}

// ------------------------------------------------------- flash attention (causal)
// attn_fwd3 (best measured: 69 us, r3). 1024 single-wave blocks (64 thr). Wave
// processes chunk pair (63-p, p), 32 q-rows each -> uniformly 33-34 KV tiles of
// 64. Fixed-base softmax: P = exp2(s - 14), no row-max / rescale. K register-
// double-buffered (prefetch next tile); V loads hide under exp phase. l via
// ones-MFMA. Only LDS: wave-private P tile (lgkmcnt-ordered, no barriers).
__device__ __forceinline__ void load_ktile(const u16* __restrict__ Kp, int t0,
                                           int l15, int lhi, bf16x8 (&kd)[8]) {
#pragma unroll
    for (int cb = 0; cb < 4; cb++) {
        const u16* kp = Kp + (size_t)(t0 + cb * 16 + l15) * 64 + lhi * 8;
        kd[cb * 2 + 0] = as_bf(*reinterpret_cast<const u16x8*>(kp));
        kd[cb * 2 + 1] = as_bf(*reinterpret_cast<const u16x8*>(kp + 32));
    }
}

__device__ __forceinline__ void attn_tile(int t0, int nt0, bool diag, int q0,
                                          const u16* __restrict__ Kp,
                                          const u16* __restrict__ Vp,
                                          int l15, int lhi,
                                          const bf16x8 (&kc_)[8], bf16x8 (&kn_)[8],
                                          const bf16x8 (&qf)[2][2], bf16x8 onesf,
                                          f32x4 (&o)[2][4], f32x4 (&os)[2],
                                          u16* __restrict__ PsW) {
    // prefetch next K tile (registers)
    load_ktile(Kp, nt0, l15, lhi, kn_);

    // QK^T; C-init = -14 folds the fixed softmax base
    f32x4 s[2][4];
#pragma unroll
    for (int qa = 0; qa < 2; qa++)
#pragma unroll
        for (int cb = 0; cb < 4; cb++) {
            f32x4 v = {-14.0f, -14.0f, -14.0f, -14.0f};
            v = __builtin_amdgcn_mfma_f32_16x16x32_bf16(qf[qa][0], kc_[cb * 2 + 0], v, 0, 0, 0);
            v = __builtin_amdgcn_mfma_f32_16x16x32_bf16(qf[qa][1], kc_[cb * 2 + 1], v, 0, 0, 0);
            s[qa][cb] = v;
        }

    // V^T fragments for THIS tile (latency hides under exp/store phase)
    bf16x8 vf[8];
#pragma unroll
    for (int db = 0; db < 4; db++)
#pragma unroll
        for (int kc2 = 0; kc2 < 2; kc2++)
            vf[db * 2 + kc2] = as_bf(*reinterpret_cast<const u16x8*>(
                Vp + (size_t)(db * 16 + l15) * 2048 + t0 + kc2 * 32 + lhi * 8));

    if (diag) {
#pragma unroll
        for (int qa = 0; qa < 2; qa++)
#pragma unroll
            for (int cb = 0; cb < 4; cb++) {
                const int tg = t0 + cb * 16 + l15;
#pragma unroll
                for (int r = 0; r < 4; r++) {
                    const int qg = q0 + qa * 16 + lhi * 4 + r;
                    if (tg > qg) s[qa][cb][r] = -1e30f;
                }
            }
    }

    // P = exp2(s), store truncated bf16 to wave-private LDS
#pragma unroll
    for (int qa = 0; qa < 2; qa++)
#pragma unroll
        for (int cb = 0; cb < 4; cb++)
#pragma unroll
            for (int r = 0; r < 4; r++) {
                float p = __builtin_amdgcn_exp2f(s[qa][cb][r]);
                unsigned pb; __builtin_memcpy(&pb, &p, 4);
                PsW[(qa * 16 + lhi * 4 + r) * 70 + cb * 16 + l15] = (u16)(pb >> 16);
            }
    asm volatile("s_waitcnt lgkmcnt(0)" ::: "memory");
    __builtin_amdgcn_sched_barrier(0);   // rule #18: keep MFMA below the waitcnt

    // PV + row-sum via ones fragment
#pragma unroll
    for (int qa = 0; qa < 2; qa++) {
        bf16x8 pf0 = as_bf(*reinterpret_cast<const u16x8*>(&PsW[(qa * 16 + l15) * 70 + lhi * 8]));
        bf16x8 pf1 = as_bf(*reinterpret_cast<const u16x8*>(&PsW[(qa * 16 + l15) * 70 + 32 + lhi * 8]));
        os[qa] = __builtin_amdgcn_mfma_f32_16x16x32_bf16(pf0, onesf, os[qa], 0, 0, 0);
        os[qa] = __builtin_amdgcn_mfma_f32_16x16x32_bf16(pf1, onesf, os[qa], 0, 0, 0);
#pragma unroll
        for (int db = 0; db < 4; db++) {
            o[qa][db] = __builtin_amdgcn_mfma_f32_16x16x32_bf16(pf0, vf[db * 2 + 0], o[qa][db], 0, 0, 0);
            o[qa][db] = __builtin_amdgcn_mfma_f32_16x16x32_bf16(pf1, vf[db * 2 + 1], o[qa][db], 0, 0, 0);
        }
    }
}

__global__ __launch_bounds__(64, 1) void attn_fwd3(const u16* __restrict__ Qb,
                                                   const u16* __restrict__ Kb,
                                                   const u16* __restrict__ VTb,
                                                   u16* __restrict__ attn_out) {
    __shared__ u16 Ps[32 * 70];
    const int lane = threadIdx.x & 63;
    const int l15 = lane & 15, lhi = lane >> 4;
    const int id = blockIdx.x;
    const int bh = (id & 7) + 8 * ((id >> 3) & 3);   // 4 heads per XCD
    const int pair = id >> 5;                        // 0..31
    const int b = bh >> 4, h = bh & 15;
    const u16* Kp = Kb + (size_t)bh * (Sc * Dc);
    const u16* Vp = VTb + (size_t)bh * (Sc * Dc);

    u16x8 onesu;
#pragma unroll
    for (int j = 0; j < 8; j++) onesu[j] = 0x3F80;
    const bf16x8 onesf = as_bf(onesu);

#pragma unroll
    for (int pass = 0; pass < 2; pass++) {
        const int qc = pass == 0 ? 63 - pair : pair;
        const int q0 = qc * 32;

        bf16x8 qf[2][2];
#pragma unroll
        for (int qa = 0; qa < 2; qa++)
#pragma unroll
            for (int kc = 0; kc < 2; kc++)
                qf[qa][kc] = as_bf(*reinterpret_cast<const u16x8*>(
                    Qb + (size_t)bh * (Sc * Dc) + (size_t)(q0 + qa * 16 + l15) * 64 + kc * 32 + lhi * 8));

        f32x4 o[2][4] = {};
        f32x4 os[2] = {};

        const int ntiles = qc / 2 + 1;
        const int last = (ntiles - 1) * 64;

        bf16x8 ka[8], kb2[8];
        load_ktile(Kp, 0, l15, lhi, ka);

        int kt = 0;
        while (true) {
            int t0 = kt * 64;
            int nt0 = (t0 < last) ? t0 + 64 : last;
            attn_tile(t0, nt0, t0 == last, q0, Kp, Vp, l15, lhi, ka, kb2, qf, onesf, o, os, Ps);
            if (++kt >= ntiles) break;
            t0 = kt * 64;
            nt0 = (t0 < last) ? t0 + 64 : last;
            attn_tile(t0, nt0, t0 == last, q0, Kp, Vp, l15, lhi, kb2, ka, qf, onesf, o, os, Ps);
            if (++kt >= ntiles) break;
        }

        // epilogue: normalize, write [B*S][E] bf16
#pragma unroll
        for (int qa = 0; qa < 2; qa++)
#pragma unroll
            for (int r = 0; r < 4; r++) {
                const int qg = q0 + qa * 16 + lhi * 4 + r;
                const float inv = 1.0f / os[qa][r];
                const size_t orow = ((size_t)(b * 2048 + qg)) * 1024 + h * 64;
#pragma unroll
                for (int db = 0; db < 4; db++)
                    attn_out[orow + db * 16 + l15] = f2bf(o[qa][db][r] * inv);
            }
    }
}

// ---------------------------------------------------------------------- launch
extern "C" void kernel_launch(void* const* d_in, const int* in_sizes, int n_in,
                              void* d_out, int out_size, void* d_ws, size_t ws_size,
                              hipStream_t stream) {
    const float* x     = (const float*)d_in[0];
    const float* w_qkv = (const float*)d_in[1];
    const float* w_out = (const float*)d_in[2];
    const float* fcos  = (const float*)d_in[3];
    const float* fsin  = (const float*)d_in[4];
    float* out = (float*)d_out;

    char* ws = (char*)d_ws;
    u16* xb    = (u16*)(ws);                       //  8,388,608 B
    u16* wqkvT = (u16*)(ws + 8388608);             //  6,291,456 B
    u16* woutT = (u16*)(ws + 14680064);            //  2,097,152 B
    u16* qkvb  = (u16*)(ws + 16777216);            // 25,165,824 B
    u16* Qb    = (u16*)(ws + 41943040);            //  8,388,608 B
    u16* Kb    = (u16*)(ws + 50331648);            //  8,388,608 B
    u16* VTb   = (u16*)(ws + 58720256);            //  8,388,608 B  (V transposed)
    u16* attnb = (u16*)(ws + 67108864);            //  8,388,608 B

    cast_f32_bf16<<<4096, 256, 0, stream>>>(x, xb, Bc * Sc * Ec);
    transpose_cast<<<dim3(96, 32), dim3(32, 32), 0, stream>>>(w_qkv, wqkvT, 1024, 3072);
    transpose_cast<<<dim3(32, 32), dim3(32, 32), 0, stream>>>(w_out, woutT, 1024, 1024);
    gemm_bt<1><<<dim3(32, 24), 256, 0, stream>>>(xb, wqkvT, qkvb, 4096, 3072, 1024);
    rope_pack<<<1024, 256, 0, stream>>>(qkvb, fcos, fsin, Qb, Kb);
    vtrans<<<dim3(32, 32), 256, 0, stream>>>(qkvb, VTb);
    attn_fwd3<<<1024, 64, 0, stream>>>(Qb, Kb, VTb, attnb);
    gemm_bt<0><<<dim3(32, 8), 256, 0, stream>>>(attnb, woutT, out, 4096, 1024, 1024);
}